// Round 3
// baseline (1025.735 us; speedup 1.0000x reference)
//
#include <hip/hip_runtime.h>

#define L 2048

// ---------------------------------------------------------------------------
// k1: pairs[i] = BASES[argmax_b feat[0, b, i, 0]]   (first-max tie break)
// ---------------------------------------------------------------------------
__global__ void pairs_kernel(const float* __restrict__ feat, float* __restrict__ pairs) {
    int i = blockIdx.x * blockDim.x + threadIdx.x;
    if (i >= L) return;
    float best = feat[(size_t)i * L];
    int bi = 0;
#pragma unroll
    for (int b = 1; b < 4; ++b) {
        float v = feat[(size_t)b * L * L + (size_t)i * L];
        if (v > best) { best = v; bi = b; }
    }
    const float BV[4] = {2.0f, 3.0f, 5.0f, 7.0f};
    pairs[i] = BV[bi];
}

// ---------------------------------------------------------------------------
// k2: one block per row i (XCD-swizzled). Collect masked positive candidates,
// bitonic-sort desc by (value, ~edge_index) == exact greedy order, emit u16
// partner list. Wave-aggregated slot allocation (1 LDS atomic per wave).
// ---------------------------------------------------------------------------
__global__ __launch_bounds__(256) void build_kernel(const float* __restrict__ con,
                                                    const float* __restrict__ pairs,
                                                    unsigned short* __restrict__ lists,
                                                    int* __restrict__ cnt,
                                                    float* __restrict__ out) {
    __shared__ unsigned long long keys[L];
    __shared__ int lcnt;
    const int bid = blockIdx.x;
    const int i = (bid & 7) * 256 + (bid >> 3);   // XCD-bijective swizzle
    const int tid = threadIdx.x;
    const int lane = tid & 63;
    if (tid == 0) lcnt = 0;
    __syncthreads();
    const float pi = pairs[i];
#pragma unroll
    for (int k = 0; k < L / 256; ++k) {
        int j = tid + k * 256;
        float a = con[(size_t)i * L + j];
        float b = con[(size_t)j * L + i];
        out[(size_t)i * L + j] = 0.0f;
        float v = 0.5f * (a + b);
        int d = i > j ? i - j : j - i;
        float pm = pi * pairs[j];
        bool valid = (d >= 4) && (pm == 14.0f || pm == 15.0f || pm == 35.0f) && (v > 0.0f);
        unsigned long long mb = __ballot(valid);
        int nww = __popcll(mb);
        if (nww) {
            int base = 0;
            if (lane == 0) base = atomicAdd(&lcnt, nww);
            base = __shfl(base, 0);
            if (valid) {
                int pos = base + __popcll(mb & ((1ull << lane) - 1ull));
                unsigned int vb = __float_as_uint(v);
                unsigned int mn = (unsigned)(i < j ? i : j);
                unsigned int mx = (unsigned)(i < j ? j : i);
                unsigned int ef = mn * (unsigned)L + mx;
                keys[pos] = ((unsigned long long)vb << 32) |
                            (unsigned long long)(0xFFFFFFFFu - ef);
            }
        }
    }
    __syncthreads();
    const int c = lcnt;
    int Np = 1;
    while (Np < c) Np <<= 1;
    if (Np < 2) Np = 2;
    for (int t = c + tid; t < Np; t += 256) keys[t] = 0ull;
    __syncthreads();
    for (int k = 2; k <= Np; k <<= 1) {
        for (int s = k >> 1; s > 0; s >>= 1) {
            for (int x = tid; x < Np; x += 256) {
                int l = x ^ s;
                if (l > x) {
                    unsigned long long a = keys[x], b = keys[l];
                    bool up = ((x & k) == 0);
                    if (up ? (a < b) : (a > b)) { keys[x] = b; keys[l] = a; }
                }
            }
            __syncthreads();
        }
    }
    for (int t = tid; t < c; t += 256) {
        unsigned int efinv = (unsigned int)(keys[t] & 0xFFFFFFFFull);
        unsigned int ef = 0xFFFFFFFFu - efinv;
        unsigned int mn = ef >> 11;
        unsigned int mx = ef & (L - 1);
        lists[(size_t)i * L + t] = (unsigned short)((mn == (unsigned)i) ? mx : mn);
    }
    if (tid == 0) cnt[i] = c;
}

// ---------------------------------------------------------------------------
// k3: mutual-best matching == sequential greedy. 256 threads, 8 rows/thread.
// Row state in REGISTERS (dead-bit mask + cached head candidate; static
// indexing via full unroll). Per-round marker store -> WRITE_SIZE encodes
// round count R (64B/round) for diagnosis.
// ---------------------------------------------------------------------------
__global__ __launch_bounds__(256) void match_kernel(const float* __restrict__ con,
                                                    const unsigned short* __restrict__ lists,
                                                    const int* __restrict__ cnt,
                                                    float* __restrict__ out,
                                                    unsigned int* __restrict__ mark) {
    __shared__ short memo[L];          // 0 free, 1 matched
    __shared__ short bestj[L];         // current proposal of each row (-1 none)
    __shared__ unsigned short pcur[L]; // scan position per row
    __shared__ unsigned int mlist[1024];
    __shared__ int nm;
    __shared__ int ch[2];
    const int tid = threadIdx.x;
    if (tid == 0) { nm = 0; ch[0] = 0; ch[1] = 0; }

    unsigned short candreg[8];   // static-index only (full unroll)
    unsigned short creg[8];
    unsigned int dead = 0;       // bit k: slot k permanently inactive

#pragma unroll
    for (int k = 0; k < 8; ++k) {
        int r = tid * 8 + k;
        memo[r] = 0;
        bestj[r] = -1;
        pcur[r] = 0;
        int c = cnt[r];
        creg[k] = (unsigned short)c;
        if (c > 0) {
            candreg[k] = lists[(size_t)r * L];   // head = best candidate
        } else {
            candreg[k] = 0;
            dead |= 1u << k;
        }
    }
    __syncthreads();

    int ph = 0;
    int rounds = 0;
    while (true) {
        // ---- pass 1: propose best free candidate (cached-head fast path) ----
        // batched read of the 8 owned rows' memo flags (16B = one LDS op)
        uint4 mw = *(const uint4*)&memo[tid * 8];
        unsigned short mown[8];
        mown[0] = (unsigned short)(mw.x & 0xFFFF);  mown[1] = (unsigned short)(mw.x >> 16);
        mown[2] = (unsigned short)(mw.y & 0xFFFF);  mown[3] = (unsigned short)(mw.y >> 16);
        mown[4] = (unsigned short)(mw.z & 0xFFFF);  mown[5] = (unsigned short)(mw.z >> 16);
        mown[6] = (unsigned short)(mw.w & 0xFFFF);  mown[7] = (unsigned short)(mw.w >> 16);
#pragma unroll
        for (int k = 0; k < 8; ++k) {
            if (dead & (1u << k)) continue;
            const int r = tid * 8 + k;
            if (mown[k]) { dead |= 1u << k; continue; }      // row got matched
            int cand = candreg[k];
            if (!memo[cand]) {                                // fast path: head still free
                bestj[r] = (short)cand;
            } else {                                          // advance scan
                int p = pcur[r] + 1;
                const int c = creg[k];
                const unsigned short* rl = lists + (size_t)r * L;
                while (p < c && memo[rl[p]]) ++p;
                if (p < c) {
                    int nc2 = rl[p];
                    candreg[k] = (unsigned short)nc2;
                    pcur[r] = (unsigned short)p;
                    bestj[r] = (short)nc2;
                } else {                                      // exhausted: never matchable
                    dead |= 1u << k;
                    bestj[r] = -1;
                }
            }
        }
        __syncthreads();   // A: proposals visible
        // ---- pass 2: mutual proposals become matches ----
        int any = 0;
#pragma unroll
        for (int k = 0; k < 8; ++k) {
            if (dead & (1u << k)) continue;
            const int r = tid * 8 + k;
            const int cand = candreg[k];
            if (bestj[cand] == (short)r && r < cand) {
                memo[r] = 1; memo[cand] = 1;
                mlist[atomicAdd(&nm, 1)] = ((unsigned)r << 16) | (unsigned)cand;
                any = 1;
            }
        }
        if (any) ch[ph] = 1;
        if (tid == 0) {
            ch[ph ^ 1] = 0;
            // round marker: one distinct dirty 64B line per round -> WRITE_SIZE
            ((volatile unsigned int*)mark)[(rounds < 2047 ? rounds : 2047) * 16] = 1u + rounds;
        }
        __syncthreads();   // B: memo/flags visible
        if (ch[ph] == 0) break;
        ph ^= 1;
        ++rounds;
    }
    __syncthreads();
    // ---- deferred emission ----
    const int m = nm;
    for (int t = tid; t < m; t += 256) {
        unsigned mp = mlist[t];
        int r = (int)(mp >> 16);
        int b = (int)(mp & 0xFFFFu);
        float v = 0.5f * (con[(size_t)r * L + b] + con[(size_t)b * L + r]);
        out[(size_t)r * L + b] = v;
        out[(size_t)b * L + r] = v;
    }
}

extern "C" void kernel_launch(void* const* d_in, const int* in_sizes, int n_in,
                              void* d_out, int out_size, void* d_ws, size_t ws_size,
                              hipStream_t stream) {
    const float* con  = (const float*)d_in[0];
    const float* feat = (const float*)d_in[1];
    float* out = (float*)d_out;
    char* ws = (char*)d_ws;
    unsigned short* lists = (unsigned short*)ws;                          // 8 MB
    size_t off = (size_t)L * L * sizeof(unsigned short);
    int*   cnt   = (int*)(ws + off);          off += L * sizeof(int);     // 8 KB
    float* pairs = (float*)(ws + off);        off += L * sizeof(float);   // 8 KB
    unsigned int* mark = (unsigned int*)(ws + off);                       // 128 KB marker

    pairs_kernel<<<(L + 255) / 256, 256, 0, stream>>>(feat, pairs);
    build_kernel<<<L, 256, 0, stream>>>(con, pairs, lists, cnt, out);
    match_kernel<<<1, 256, 0, stream>>>(con, lists, cnt, out, mark);
}

// Round 4
// 579.670 us; speedup vs baseline: 1.7695x; 1.7695x over previous
//
#include <hip/hip_runtime.h>

#define L 2048

// ---------------------------------------------------------------------------
// k1: pairs[i] = BASES[argmax_b feat[0, b, i, 0]]   (first-max tie break)
// ---------------------------------------------------------------------------
__global__ void pairs_kernel(const float* __restrict__ feat, float* __restrict__ pairs) {
    int i = blockIdx.x * blockDim.x + threadIdx.x;
    if (i >= L) return;
    float best = feat[(size_t)i * L];
    int bi = 0;
#pragma unroll
    for (int b = 1; b < 4; ++b) {
        float v = feat[(size_t)b * L * L + (size_t)i * L];
        if (v > best) { best = v; bi = b; }
    }
    const float BV[4] = {2.0f, 3.0f, 5.0f, 7.0f};
    pairs[i] = BV[bi];
}

// ---------------------------------------------------------------------------
// k1b: tiled symmetrize + fold ALL masks:
//   sym[i][j] = v = 0.5*(con[i][j]+con[j][i]) if |i-j|>=4 && pm in {14,15,35}
//               && v>0, else 0.  Coalesced both directions via LDS transpose.
// ---------------------------------------------------------------------------
__global__ __launch_bounds__(256) void sym_kernel(const float* __restrict__ con,
                                                  const float* __restrict__ pairs,
                                                  float* __restrict__ sym) {
    const int ti = blockIdx.x, tj = blockIdx.y;
    if (tj < ti) return;                         // upper-tri tile pairs only
    __shared__ float ldsB[64][65];
    __shared__ float ldsS[64][65];
    __shared__ float pr[64], pc[64];
    const int tid = threadIdx.x;
    const int c = tid & 63, r4 = tid >> 6;
    if (tid < 64) { pr[tid] = pairs[ti * 64 + tid]; pc[tid] = pairs[tj * 64 + tid]; }
#pragma unroll
    for (int rr = r4; rr < 64; rr += 4)          // B tile = con[tj-block rows, ti-block cols]
        ldsB[rr][c] = con[(size_t)(tj * 64 + rr) * L + ti * 64 + c];
    __syncthreads();
#pragma unroll
    for (int rr = r4; rr < 64; rr += 4) {
        int gi = ti * 64 + rr, gj = tj * 64 + c;
        float a = con[(size_t)gi * L + gj];
        float v = 0.5f * (a + ldsB[c][rr]);      // (c+rr)%32 banks: conflict-free
        float pm = pr[rr] * pc[c];
        int d = gi > gj ? gi - gj : gj - gi;
        bool ok = (d >= 4) && (pm == 14.0f || pm == 15.0f || pm == 35.0f) && (v > 0.0f);
        ldsS[rr][c] = ok ? v : 0.0f;
    }
    __syncthreads();
#pragma unroll
    for (int rr = r4; rr < 64; rr += 4)
        sym[(size_t)(ti * 64 + rr) * L + tj * 64 + c] = ldsS[rr][c];
    if (ti != tj) {
#pragma unroll
        for (int rr = r4; rr < 64; rr += 4)
            sym[(size_t)(tj * 64 + rr) * L + ti * 64 + c] = ldsS[c][rr];
    }
}

// ---------------------------------------------------------------------------
// k2a (sym path): row i: read masked row coalesced, compact candidates,
// bitonic-sort desc by (value, ~edge_index) == greedy order, emit u16 list.
// ---------------------------------------------------------------------------
__global__ __launch_bounds__(256) void build_sym_kernel(const float* __restrict__ sym,
                                                        unsigned short* __restrict__ lists,
                                                        int* __restrict__ cnt,
                                                        float* __restrict__ out) {
    __shared__ unsigned long long keys[L];
    __shared__ int lcnt;
    const int bid = blockIdx.x;
    const int i = (bid & 7) * 256 + (bid >> 3);
    const int tid = threadIdx.x;
    const int lane = tid & 63;
    if (tid == 0) lcnt = 0;
    __syncthreads();
    const float4* srow = (const float4*)(sym + (size_t)i * L);
    float4* orow = (float4*)(out + (size_t)i * L);
#pragma unroll
    for (int k = 0; k < 2; ++k) {
        int q = tid + k * 256;                   // float4 index
        float4 v4 = srow[q];
        orow[q] = make_float4(0.f, 0.f, 0.f, 0.f);
#pragma unroll
        for (int e = 0; e < 4; ++e) {
            float v = (e == 0) ? v4.x : (e == 1) ? v4.y : (e == 2) ? v4.z : v4.w;
            int j = q * 4 + e;
            bool valid = v > 0.0f;
            unsigned long long mb = __ballot(valid);
            if (mb) {
                int base = 0;
                if (lane == 0) base = atomicAdd(&lcnt, __popcll(mb));
                base = __shfl(base, 0);
                if (valid) {
                    int pos = base + __popcll(mb & ((1ull << lane) - 1ull));
                    unsigned int vb = __float_as_uint(v);
                    unsigned int mn = (unsigned)(i < j ? i : j);
                    unsigned int mx = (unsigned)(i < j ? j : i);
                    unsigned int ef = mn * (unsigned)L + mx;
                    keys[pos] = ((unsigned long long)vb << 32) |
                                (unsigned long long)(0xFFFFFFFFu - ef);
                }
            }
        }
    }
    __syncthreads();
    const int c = lcnt;
    int Np = 1;
    while (Np < c) Np <<= 1;
    if (Np < 2) Np = 2;
    for (int t = c + tid; t < Np; t += 256) keys[t] = 0ull;
    __syncthreads();
    for (int k = 2; k <= Np; k <<= 1) {
        for (int s = k >> 1; s > 0; s >>= 1) {
            for (int x = tid; x < Np; x += 256) {
                int l = x ^ s;
                if (l > x) {
                    unsigned long long a = keys[x], b = keys[l];
                    bool up = ((x & k) == 0);
                    if (up ? (a < b) : (a > b)) { keys[x] = b; keys[l] = a; }
                }
            }
            __syncthreads();
        }
    }
    for (int t = tid; t < c; t += 256) {
        unsigned int ef = 0xFFFFFFFFu - (unsigned int)(keys[t] & 0xFFFFFFFFull);
        unsigned int mn = ef >> 11;
        unsigned int mx = ef & (L - 1);
        lists[(size_t)i * L + t] = (unsigned short)((mn == (unsigned)i) ? mx : mn);
    }
    if (tid == 0) cnt[i] = c;
}

// ---------------------------------------------------------------------------
// k2b (fallback, ws too small): old gather build
// ---------------------------------------------------------------------------
__global__ __launch_bounds__(256) void build_gather_kernel(const float* __restrict__ con,
                                                           const float* __restrict__ pairs,
                                                           unsigned short* __restrict__ lists,
                                                           int* __restrict__ cnt,
                                                           float* __restrict__ out) {
    __shared__ unsigned long long keys[L];
    __shared__ int lcnt;
    const int bid = blockIdx.x;
    const int i = (bid & 7) * 256 + (bid >> 3);
    const int tid = threadIdx.x;
    const int lane = tid & 63;
    if (tid == 0) lcnt = 0;
    __syncthreads();
    const float pi = pairs[i];
#pragma unroll
    for (int k = 0; k < L / 256; ++k) {
        int j = tid + k * 256;
        float a = con[(size_t)i * L + j];
        float b = con[(size_t)j * L + i];
        out[(size_t)i * L + j] = 0.0f;
        float v = 0.5f * (a + b);
        int d = i > j ? i - j : j - i;
        float pm = pi * pairs[j];
        bool valid = (d >= 4) && (pm == 14.0f || pm == 15.0f || pm == 35.0f) && (v > 0.0f);
        unsigned long long mb = __ballot(valid);
        if (mb) {
            int base = 0;
            if (lane == 0) base = atomicAdd(&lcnt, __popcll(mb));
            base = __shfl(base, 0);
            if (valid) {
                int pos = base + __popcll(mb & ((1ull << lane) - 1ull));
                unsigned int vb = __float_as_uint(v);
                unsigned int mn = (unsigned)(i < j ? i : j);
                unsigned int mx = (unsigned)(i < j ? j : i);
                unsigned int ef = mn * (unsigned)L + mx;
                keys[pos] = ((unsigned long long)vb << 32) |
                            (unsigned long long)(0xFFFFFFFFu - ef);
            }
        }
    }
    __syncthreads();
    const int c = lcnt;
    int Np = 1;
    while (Np < c) Np <<= 1;
    if (Np < 2) Np = 2;
    for (int t = c + tid; t < Np; t += 256) keys[t] = 0ull;
    __syncthreads();
    for (int k = 2; k <= Np; k <<= 1) {
        for (int s = k >> 1; s > 0; s >>= 1) {
            for (int x = tid; x < Np; x += 256) {
                int l = x ^ s;
                if (l > x) {
                    unsigned long long a = keys[x], b = keys[l];
                    bool up = ((x & k) == 0);
                    if (up ? (a < b) : (a > b)) { keys[x] = b; keys[l] = a; }
                }
            }
            __syncthreads();
        }
    }
    for (int t = tid; t < c; t += 256) {
        unsigned int ef = 0xFFFFFFFFu - (unsigned int)(keys[t] & 0xFFFFFFFFull);
        unsigned int mn = ef >> 11;
        unsigned int mx = ef & (L - 1);
        lists[(size_t)i * L + t] = (unsigned short)((mn == (unsigned)i) ? mx : mn);
    }
    if (tid == 0) cnt[i] = c;
}

// ---------------------------------------------------------------------------
// k3: v2 match kernel VERBATIM + per-round fixed-cost volatile-LDS chase
// (~16 dependent reads ≈ 1.9K cy) as a time-domain round counter.
//   R≈15  -> match ~360-380 µs (delay invisible)
//   R≈1000-> match ~1150-1250 µs
// halve=1: v = 0.5*(val[r][b]+val[b][r]) (con); halve=0: v = val[r][b] (sym).
// ---------------------------------------------------------------------------
__global__ __launch_bounds__(1024) void match_kernel(const float* __restrict__ val,
                                                     const unsigned short* __restrict__ lists,
                                                     const int* __restrict__ cnt,
                                                     float* __restrict__ out,
                                                     int halve) {
    __shared__ short memo[L];
    __shared__ short bestj[L];
    __shared__ unsigned int matched[1024];
    __shared__ int nm;
    __shared__ int ch[2];
    __shared__ int chaseA[1024];
    const int tid = threadIdx.x;
    const int r0 = tid, r1 = tid + 1024;
    memo[r0] = 0; memo[r1] = 0;
    chaseA[tid] = tid + 1;
    if (tid == 0) { nm = 0; ch[0] = 0; ch[1] = 0; }
    int p0 = 0, p1 = 0;
    const int c0 = cnt[r0], c1 = cnt[r1];
    const uint4* row0 = reinterpret_cast<const uint4*>(lists + (size_t)r0 * L);
    const uint4* row1 = reinterpret_cast<const uint4*>(lists + (size_t)r1 * L);
    uint4 buf0, buf1;
    int cb0 = -1, cb1 = -1;
    int ph = 0;
    int rnds = 0;
    int x = tid & 255;
    volatile int* chv = chaseA;
    __syncthreads();
    while (true) {
        // ---- fixed-cost round probe: 16 dependent volatile LDS reads ----
#pragma unroll
        for (int u = 0; u < 16; ++u) x = chv[(x + u + rnds) & 1023];
        // ---- phase 1: each free row proposes its best free partner ----
        int b0 = -1, b1 = -1;
        if (!memo[r0]) {
            while (p0 < c0) {
                int nc = p0 >> 3;
                if (nc != cb0) { buf0 = row0[nc]; cb0 = nc; }
                int sl = p0 & 7;
                unsigned w = (sl < 4) ? ((sl < 2) ? buf0.x : buf0.y)
                                      : ((sl < 6) ? buf0.z : buf0.w);
                int cand = (int)((w >> ((sl & 1) * 16)) & 0xFFFFu);
                if (!memo[cand]) { b0 = cand; break; }
                ++p0;
            }
        }
        if (!memo[r1]) {
            while (p1 < c1) {
                int nc = p1 >> 3;
                if (nc != cb1) { buf1 = row1[nc]; cb1 = nc; }
                int sl = p1 & 7;
                unsigned w = (sl < 4) ? ((sl < 2) ? buf1.x : buf1.y)
                                      : ((sl < 6) ? buf1.z : buf1.w);
                int cand = (int)((w >> ((sl & 1) * 16)) & 0xFFFFu);
                if (!memo[cand]) { b1 = cand; break; }
                ++p1;
            }
        }
        bestj[r0] = (short)b0; bestj[r1] = (short)b1;
        __syncthreads();            // A: proposals visible
        // ---- phase 2: mutual proposals become matches (record only) ----
        if (b0 >= 0 && r0 < b0 && bestj[b0] == (short)r0) {
            memo[r0] = 1; memo[b0] = 1;
            matched[atomicAdd(&nm, 1)] = ((unsigned)r0 << 16) | (unsigned)p0;
            ch[ph] = 1;
        }
        if (b1 >= 0 && r1 < b1 && bestj[b1] == (short)r1) {
            memo[r1] = 1; memo[b1] = 1;
            matched[atomicAdd(&nm, 1)] = ((unsigned)r1 << 16) | (unsigned)p1;
            ch[ph] = 1;
        }
        if (tid == 0) ch[ph ^ 1] = 0;
        __syncthreads();            // B: memo/matched/flag visible
        if (ch[ph] == 0) break;
        ph ^= 1;
        ++rnds;
    }
    __syncthreads();
    // ---- deferred emission ----
    const int m = nm;
    for (int t = tid; t < m; t += 1024) {
        unsigned mp = matched[t];
        int r = (int)(mp >> 16);
        int p = (int)(mp & 0xFFFFu);
        int b = (int)lists[(size_t)r * L + p];
        float v;
        if (halve) v = 0.5f * (val[(size_t)r * L + b] + val[(size_t)b * L + r]);
        else       v = val[(size_t)r * L + b];
        out[(size_t)r * L + b] = v;
        out[(size_t)b * L + r] = v;
    }
    // sink for the chase (x < 4096 always; keeps volatile chain meaningful)
    if (x == 123456789) out[0] = 1.0f;
}

extern "C" void kernel_launch(void* const* d_in, const int* in_sizes, int n_in,
                              void* d_out, int out_size, void* d_ws, size_t ws_size,
                              hipStream_t stream) {
    const float* con  = (const float*)d_in[0];
    const float* feat = (const float*)d_in[1];
    float* out = (float*)d_out;
    char* ws = (char*)d_ws;
    unsigned short* lists = (unsigned short*)ws;                          // 8 MB
    size_t off = (size_t)L * L * sizeof(unsigned short);
    int*   cnt   = (int*)(ws + off);   off += L * sizeof(int);
    float* pairs = (float*)(ws + off); off += L * sizeof(float);
    float* sym   = (float*)(ws + off); off += (size_t)L * L * sizeof(float); // 16 MB
    const bool use_sym = ws_size >= off;

    pairs_kernel<<<(L + 255) / 256, 256, 0, stream>>>(feat, pairs);
    if (use_sym) {
        sym_kernel<<<dim3(32, 32), 256, 0, stream>>>(con, pairs, sym);
        build_sym_kernel<<<L, 256, 0, stream>>>(sym, lists, cnt, out);
        match_kernel<<<1, 1024, 0, stream>>>(sym, lists, cnt, out, 0);
    } else {
        build_gather_kernel<<<L, 256, 0, stream>>>(con, pairs, lists, cnt, out);
        match_kernel<<<1, 1024, 0, stream>>>(con, lists, cnt, out, 1);
    }
}

// Round 12
// 446.748 us; speedup vs baseline: 2.2960x; 1.2975x over previous
//
#include <hip/hip_runtime.h>

#define L 2048

// ---------------------------------------------------------------------------
// k1: pairs[i] = BASES[argmax_b feat[0, b, i, 0]]   (first-max tie break)
// ---------------------------------------------------------------------------
__global__ void pairs_kernel(const float* __restrict__ feat, float* __restrict__ pairs) {
    int i = blockIdx.x * blockDim.x + threadIdx.x;
    if (i >= L) return;
    float best = feat[(size_t)i * L];
    int bi = 0;
#pragma unroll
    for (int b = 1; b < 4; ++b) {
        float v = feat[(size_t)b * L * L + (size_t)i * L];
        if (v > best) { best = v; bi = b; }
    }
    const float BV[4] = {2.0f, 3.0f, 5.0f, 7.0f};
    pairs[i] = BV[bi];
}

// ---------------------------------------------------------------------------
// k2: one block per row i (XCD-swizzled) — VERBATIM round-2 (passed).
// ---------------------------------------------------------------------------
__global__ __launch_bounds__(256) void build_kernel(const float* __restrict__ con,
                                                    const float* __restrict__ pairs,
                                                    unsigned short* __restrict__ lists,
                                                    int* __restrict__ cnt,
                                                    float* __restrict__ out) {
    __shared__ unsigned long long keys[L];
    __shared__ int lcnt;
    const int bid = blockIdx.x;
    const int i = (bid & 7) * 256 + (bid >> 3);   // XCD-bijective swizzle (2048 = 8*256)
    const int tid = threadIdx.x;
    if (tid == 0) lcnt = 0;
    __syncthreads();
    const float pi = pairs[i];
#pragma unroll
    for (int k = 0; k < L / 256; ++k) {
        int j = tid + k * 256;
        float a = con[(size_t)i * L + j];          // coalesced row read
        float b = con[(size_t)j * L + i];          // transpose gather (L2/LLC)
        out[(size_t)i * L + j] = 0.0f;             // pre-zero output row
        float v = 0.5f * (a + b);
        int d = i > j ? i - j : j - i;
        float pm = pi * pairs[j];
        bool valid = (d >= 4) && (pm == 14.0f || pm == 15.0f || pm == 35.0f) && (v > 0.0f);
        if (valid) {
            int pos = atomicAdd(&lcnt, 1);
            unsigned int vb = __float_as_uint(v);              // positive: bit order == value order
            unsigned int mn = (unsigned)(i < j ? i : j);
            unsigned int mx = (unsigned)(i < j ? j : i);
            unsigned int ef = mn * (unsigned)L + mx;           // < 2^22
            keys[pos] = ((unsigned long long)vb << 32) |
                        (unsigned long long)(0xFFFFFFFFu - ef); // value desc, then ef asc
        }
    }
    __syncthreads();
    const int c = lcnt;
    int Np = 1;
    while (Np < c) Np <<= 1;
    if (Np < 2) Np = 2;
    for (int t = c + tid; t < Np; t += 256) keys[t] = 0ull;
    __syncthreads();
    // bitonic sort, descending
    for (int k = 2; k <= Np; k <<= 1) {
        for (int s = k >> 1; s > 0; s >>= 1) {
            for (int x = tid; x < Np; x += 256) {
                int l = x ^ s;
                if (l > x) {
                    unsigned long long a = keys[x], b = keys[l];
                    bool up = ((x & k) == 0);
                    if (up ? (a < b) : (a > b)) { keys[x] = b; keys[l] = a; }
                }
            }
            __syncthreads();
        }
    }
    for (int t = tid; t < c; t += 256) {
        unsigned int ef = 0xFFFFFFFFu - (unsigned int)(keys[t] & 0xFFFFFFFFull);
        unsigned int mn = ef >> 11;          // /L
        unsigned int mx = ef & (L - 1);      // %L
        lists[(size_t)i * L + t] = (unsigned short)((mn == (unsigned)i) ? mx : mn);
    }
    if (tid == 0) cnt[i] = c;
}

// ---------------------------------------------------------------------------
// k3: mutual-best matching == sequential greedy. 1024 threads, 2 rows/thread.
// ROUND-2 PASSING KERNEL with ONE structural change: the per-round scan is
// bounded to an 8-entry WINDOW (same loop body, tighter bound). Rows mid-scan
// don't propose that round; a 'progress' parity flag defers exit until no
// match AND no pointer advance. Proposals are always true first-free
// candidates, so the final matching is unchanged (= sequential greedy).
// Rationale: per-round cost is divergence-serialized issue (wave pays the
// union of its 64 lanes' scan iterations); the window caps that union.
// ---------------------------------------------------------------------------
__global__ __launch_bounds__(1024) void match_kernel(const float* __restrict__ con,
                                                     const unsigned short* __restrict__ lists,
                                                     const int* __restrict__ cnt,
                                                     float* __restrict__ out) {
    __shared__ short memo[L];
    __shared__ short bestj[L];
    __shared__ unsigned int matched[1024];
    __shared__ int nm;
    __shared__ int ch[2];
    __shared__ int pg[2];
    const int tid = threadIdx.x;
    const int r0 = tid, r1 = tid + 1024;
    memo[r0] = 0; memo[r1] = 0;
    if (tid == 0) { nm = 0; ch[0] = 0; ch[1] = 0; pg[0] = 0; pg[1] = 0; }
    int p0 = 0, p1 = 0;
    const int c0 = cnt[r0], c1 = cnt[r1];
    const uint4* row0 = reinterpret_cast<const uint4*>(lists + (size_t)r0 * L);
    const uint4* row1 = reinterpret_cast<const uint4*>(lists + (size_t)r1 * L);
    uint4 buf0, buf1;
    int cb0 = -1, cb1 = -1;
    int ph = 0;
    __syncthreads();
    while (true) {
        // ---- phase 1: each free row scans ≤8 entries toward its first free ----
        int b0 = -1, b1 = -1;
        if (!memo[r0]) {
            int wend0 = (p0 + 8 < c0) ? p0 + 8 : c0;
            while (p0 < wend0) {
                int nc = p0 >> 3;
                if (nc != cb0) { buf0 = row0[nc]; cb0 = nc; }
                int sl = p0 & 7;
                unsigned w = (sl < 4) ? ((sl < 2) ? buf0.x : buf0.y)
                                      : ((sl < 6) ? buf0.z : buf0.w);
                int cand = (int)((w >> ((sl & 1) * 16)) & 0xFFFFu);
                if (!memo[cand]) { b0 = cand; break; }
                ++p0;
            }
            if (b0 < 0 && p0 < c0) pg[ph] = 1;   // mid-scan: advanced, not done
        }
        if (!memo[r1]) {
            int wend1 = (p1 + 8 < c1) ? p1 + 8 : c1;
            while (p1 < wend1) {
                int nc = p1 >> 3;
                if (nc != cb1) { buf1 = row1[nc]; cb1 = nc; }
                int sl = p1 & 7;
                unsigned w = (sl < 4) ? ((sl < 2) ? buf1.x : buf1.y)
                                      : ((sl < 6) ? buf1.z : buf1.w);
                int cand = (int)((w >> ((sl & 1) * 16)) & 0xFFFFu);
                if (!memo[cand]) { b1 = cand; break; }
                ++p1;
            }
            if (b1 < 0 && p1 < c1) pg[ph] = 1;
        }
        bestj[r0] = (short)b0;          // unconditional, every row, every round
        bestj[r1] = (short)b1;
        __syncthreads();            // A: proposals visible
        // ---- phase 2: mutual proposals become matches (record only) ----
        if (b0 >= 0 && r0 < b0 && bestj[b0] == (short)r0) {
            memo[r0] = 1; memo[b0] = 1;
            matched[atomicAdd(&nm, 1)] = ((unsigned)r0 << 16) | (unsigned)p0;
            ch[ph] = 1;
        }
        if (b1 >= 0 && r1 < b1 && bestj[b1] == (short)r1) {
            memo[r1] = 1; memo[b1] = 1;
            matched[atomicAdd(&nm, 1)] = ((unsigned)r1 << 16) | (unsigned)p1;
            ch[ph] = 1;
        }
        if (tid == 0) { ch[ph ^ 1] = 0; pg[ph ^ 1] = 0; }   // prep next round's flags
        __syncthreads();            // B: memo/matched/flags visible
        if (ch[ph] == 0 && pg[ph] == 0) break;   // uniform exit: no match, no progress
        ph ^= 1;
    }
    __syncthreads();
    // ---- deferred emission: con gathers + out scatters off the round path ----
    const int m = nm;
    for (int t = tid; t < m; t += 1024) {
        unsigned mp = matched[t];
        int r = (int)(mp >> 16);
        int p = (int)(mp & 0xFFFFu);
        int b = (int)lists[(size_t)r * L + p];
        float v = 0.5f * (con[(size_t)r * L + b] + con[(size_t)b * L + r]);
        out[(size_t)r * L + b] = v;
        out[(size_t)b * L + r] = v;
    }
}

extern "C" void kernel_launch(void* const* d_in, const int* in_sizes, int n_in,
                              void* d_out, int out_size, void* d_ws, size_t ws_size,
                              hipStream_t stream) {
    const float* con  = (const float*)d_in[0];
    const float* feat = (const float*)d_in[1];
    float* out = (float*)d_out;
    char* ws = (char*)d_ws;
    unsigned short* lists = (unsigned short*)ws;                         // 8 MB
    size_t off = (size_t)L * L * sizeof(unsigned short);
    int*   cnt   = (int*)(ws + off);   off += L * sizeof(int);           // 8 KB
    float* pairs = (float*)(ws + off);                                   // 8 KB

    pairs_kernel<<<(L + 255) / 256, 256, 0, stream>>>(feat, pairs);
    build_kernel<<<L, 256, 0, stream>>>(con, pairs, lists, cnt, out);
    match_kernel<<<1, 1024, 0, stream>>>(con, lists, cnt, out);
}